// Round 2
// baseline (409.414 us; speedup 1.0000x reference)
//
#include <hip/hip_runtime.h>
#include <math.h>

// Problem constants (B=64, C=128, H=W=56)
#define HW 3136
#define NCHUNK 3136          // 64 batches * 49 chunks of 64 samples
#define M_TOT 200704.0f
#define EPSV 1e-5f

typedef __attribute__((ext_vector_type(8))) short bf16x8;
typedef __attribute__((ext_vector_type(4))) short short4v;
typedef __attribute__((ext_vector_type(4))) float f32x4;

__device__ inline unsigned short f2bf(float f) {  // RNE fp32->bf16
  unsigned u = __float_as_uint(f);
  u += 0x7FFFu + ((u >> 16) & 1u);
  return (unsigned short)(u >> 16);
}

// ---------------------------------------------------------------------------
// Kernel 1: partial Gram (X @ X^T) + channel sums, bf16 MFMA 16x16x32.
// grid = slots (512), block = 512 (8 waves -> 16 waves/CU at 2 blocks/CU).
// Double-buffered LDS + VGPR prefetch; ONE barrier per iteration.
// Channel sums -> partS[slot][ch] plain stores (round-1 atomicAdd to S[128]
// was a ~30us serialization tail: 65K device atomics on 4 cache lines).
// D layout (m89): col = lane&15, row = quad*4 + reg.
// ---------------------------------------------------------------------------
__global__ __launch_bounds__(512, 4) void gram_k(const float* __restrict__ x,
                                                 float* __restrict__ partG,
                                                 float* __restrict__ partS,
                                                 int slots) {
  __shared__ unsigned short xs[2][128 * 72];  // 2 x 18432 B
  const int t = threadIdx.x;
  const int lm = t & 15, quad = (t >> 4) & 3, w = t >> 6;  // w = 0..7
  const int row0 = w * 16;
  const int qofs = (t & 15) * 4;   // sample-quad offset for staging
  const int chi = t >> 4;          // 0..31 channel sub-index for staging

  f32x4 acc[8];
  f32x4 sacc;
  const f32x4 z = {0.f, 0.f, 0.f, 0.f};
  sacc = z;
#pragma unroll
  for (int j = 0; j < 8; ++j) acc[j] = z;
  bf16x8 ones;
#pragma unroll
  for (int j = 0; j < 8; ++j) ones[j] = (short)0x3F80;  // bf16 1.0

  int chunk = blockIdx.x;
  float4 pre[4];
  {
    const int b = chunk / 49;
    const int s0 = (chunk % 49) * 64;
    const float* base = x + (size_t)(b * 128) * HW + s0;
#pragma unroll
    for (int i = 0; i < 4; ++i)
      pre[i] = *(const float4*)(base + (size_t)(i * 32 + chi) * HW + qofs);
  }

  int buf = 0;
  while (chunk < NCHUNK) {
    // stage prefetched chunk -> xs[buf]
#pragma unroll
    for (int i = 0; i < 4; ++i) {
      const int c = i * 32 + chi;
      uint2 dw;
      dw.x = (unsigned)f2bf(pre[i].x) | ((unsigned)f2bf(pre[i].y) << 16);
      dw.y = (unsigned)f2bf(pre[i].z) | ((unsigned)f2bf(pre[i].w) << 16);
      *(uint2*)&xs[buf][c * 72 + qofs] = dw;
    }
    __syncthreads();
    // prefetch next chunk (drains during MFMA below)
    const int nxt = chunk + slots;
    if (nxt < NCHUNK) {
      const int b = nxt / 49;
      const int s0 = (nxt % 49) * 64;
      const float* base = x + (size_t)(b * 128) * HW + s0;
#pragma unroll
      for (int i = 0; i < 4; ++i)
        pre[i] = *(const float4*)(base + (size_t)(i * 32 + chi) * HW + qofs);
    }
    // compute from xs[buf]
#pragma unroll
    for (int ks = 0; ks < 2; ++ks) {
      const int ko = ks * 32 + quad * 8;
      const bf16x8 a0 = *(const bf16x8*)&xs[buf][(row0 + lm) * 72 + ko];
      sacc = __builtin_amdgcn_mfma_f32_16x16x32_bf16(a0, ones, sacc, 0, 0, 0);
#pragma unroll
      for (int tj = 0; tj < 8; ++tj) {
        const bf16x8 bf = *(const bf16x8*)&xs[buf][(tj * 16 + lm) * 72 + ko];
        acc[tj] = __builtin_amdgcn_mfma_f32_16x16x32_bf16(a0, bf, acc[tj], 0, 0, 0);
      }
    }
    buf ^= 1;
    chunk = nxt;
  }

  float* pg = partG + (size_t)blockIdx.x * 16384;
#pragma unroll
  for (int tj = 0; tj < 8; ++tj)
#pragma unroll
    for (int r = 0; r < 4; ++r)
      pg[(row0 + quad * 4 + r) * 128 + tj * 16 + lm] = acc[tj][r];
  if (lm == 0) {
#pragma unroll
    for (int r = 0; r < 4; ++r)
      partS[blockIdx.x * 128 + row0 + quad * 4 + r] = sacc[r];
  }
}

// ---------------------------------------------------------------------------
// Software grid barrier (all blocks co-resident: grid <= 256 CUs, 1 blk/CU).
// Device-scope arrive + acquire spin; __threadfence() = agent fence handles
// cross-XCD L2 writeback/invalidate. Fresh counter per barrier (memset 0).
// ---------------------------------------------------------------------------
__device__ inline void gbar(unsigned* c, unsigned n) {
  __syncthreads();
  __threadfence();
  if (threadIdx.x == 0) {
    __hip_atomic_fetch_add(c, 1u, __ATOMIC_RELEASE, __HIP_MEMORY_SCOPE_AGENT);
    while (__hip_atomic_load(c, __ATOMIC_ACQUIRE, __HIP_MEMORY_SCOPE_AGENT) < n)
      __builtin_amdgcn_s_sleep(8);
  }
  __syncthreads();
  __threadfence();
}

// ---------------------------------------------------------------------------
// Newton step (256 threads, blocks 0..15, 8 output rows each):
// Pout = 0.5*(3P - ((P@P)@P)@(rTr*Sigma)). P symmetric.
// ---------------------------------------------------------------------------
__device__ inline void newton_step(const float* __restrict__ P,
                                   const float* __restrict__ Sig,
                                   float rTr, float* __restrict__ Pout,
                                   int rg0, int t, float* s1, float* s2,
                                   float* red) {
  const int ct = t & 31;
  const int rt = (t >> 5) & 1;
  const int kt = t >> 6;
  float a[4][4];

  // phase 1: s1 = strip(P @ P)
#pragma unroll
  for (int i = 0; i < 4; ++i)
#pragma unroll
    for (int j = 0; j < 4; ++j) a[i][j] = 0.f;
#pragma unroll 4
  for (int k = kt * 32; k < kt * 32 + 32; ++k) {
    const float4 av = *(const float4*)(P + k * 128 + rg0 + 4 * rt);  // symmetry
    const float4 bv = *(const float4*)(P + k * 128 + 4 * ct);
    const float aA[4] = {av.x, av.y, av.z, av.w};
    const float bA[4] = {bv.x, bv.y, bv.z, bv.w};
#pragma unroll
    for (int i = 0; i < 4; ++i)
#pragma unroll
      for (int j = 0; j < 4; ++j) a[i][j] += aA[i] * bA[j];
  }
#pragma unroll
  for (int i = 0; i < 4; ++i)
#pragma unroll
    for (int j = 0; j < 4; ++j) red[t * 17 + i * 4 + j] = a[i][j];
  __syncthreads();
  if (t < 64) {
#pragma unroll
    for (int u = 1; u < 4; ++u)
#pragma unroll
      for (int i = 0; i < 4; ++i)
#pragma unroll
        for (int j = 0; j < 4; ++j)
          a[i][j] += red[(t + 64 * u) * 17 + i * 4 + j];
#pragma unroll
    for (int i = 0; i < 4; ++i)
#pragma unroll
      for (int j = 0; j < 4; ++j)
        s1[(4 * rt + i) * 132 + 4 * ct + j] = a[i][j];
  }
  __syncthreads();

  // phase 2: s2 = s1 @ P
#pragma unroll
  for (int i = 0; i < 4; ++i)
#pragma unroll
    for (int j = 0; j < 4; ++j) a[i][j] = 0.f;
#pragma unroll 4
  for (int k = kt * 32; k < kt * 32 + 32; ++k) {
    float aA[4];
#pragma unroll
    for (int i = 0; i < 4; ++i) aA[i] = s1[(4 * rt + i) * 132 + k];
    const float4 bv = *(const float4*)(P + k * 128 + 4 * ct);
    const float bA[4] = {bv.x, bv.y, bv.z, bv.w};
#pragma unroll
    for (int i = 0; i < 4; ++i)
#pragma unroll
      for (int j = 0; j < 4; ++j) a[i][j] += aA[i] * bA[j];
  }
  __syncthreads();
#pragma unroll
  for (int i = 0; i < 4; ++i)
#pragma unroll
    for (int j = 0; j < 4; ++j) red[t * 17 + i * 4 + j] = a[i][j];
  __syncthreads();
  if (t < 64) {
#pragma unroll
    for (int u = 1; u < 4; ++u)
#pragma unroll
      for (int i = 0; i < 4; ++i)
#pragma unroll
        for (int j = 0; j < 4; ++j)
          a[i][j] += red[(t + 64 * u) * 17 + i * 4 + j];
#pragma unroll
    for (int i = 0; i < 4; ++i)
#pragma unroll
      for (int j = 0; j < 4; ++j)
        s2[(4 * rt + i) * 132 + 4 * ct + j] = a[i][j];
  }
  __syncthreads();

  // phase 3: a = s2 @ Sigma_raw; Pout = 0.5*(3P - rTr*a)
#pragma unroll
  for (int i = 0; i < 4; ++i)
#pragma unroll
    for (int j = 0; j < 4; ++j) a[i][j] = 0.f;
#pragma unroll 4
  for (int k = kt * 32; k < kt * 32 + 32; ++k) {
    float aA[4];
#pragma unroll
    for (int i = 0; i < 4; ++i) aA[i] = s2[(4 * rt + i) * 132 + k];
    const float4 bv = *(const float4*)(Sig + k * 128 + 4 * ct);
    const float bA[4] = {bv.x, bv.y, bv.z, bv.w};
#pragma unroll
    for (int i = 0; i < 4; ++i)
#pragma unroll
      for (int j = 0; j < 4; ++j) a[i][j] += aA[i] * bA[j];
  }
  __syncthreads();
#pragma unroll
  for (int i = 0; i < 4; ++i)
#pragma unroll
    for (int j = 0; j < 4; ++j) red[t * 17 + i * 4 + j] = a[i][j];
  __syncthreads();
  if (t < 64) {
#pragma unroll
    for (int u = 1; u < 4; ++u)
#pragma unroll
      for (int i = 0; i < 4; ++i)
#pragma unroll
        for (int j = 0; j < 4; ++j)
          a[i][j] += red[(t + 64 * u) * 17 + i * 4 + j];
#pragma unroll
    for (int i = 0; i < 4; ++i) {
      const int rg = rg0 + 4 * rt + i;
      const float4 pv = *(const float4*)(P + rg * 128 + 4 * ct);
      *(float4*)(Pout + rg * 128 + 4 * ct) =
          make_float4(0.5f * (3.f * pv.x - rTr * a[i][0]),
                      0.5f * (3.f * pv.y - rTr * a[i][1]),
                      0.5f * (3.f * pv.z - rTr * a[i][2]),
                      0.5f * (3.f * pv.w - rTr * a[i][3]));
    }
  }
}

// ---------------------------------------------------------------------------
// First+second Newton step fused (P1 = 1.5I - 0.5*rTr*Sigma synthesized).
// ---------------------------------------------------------------------------
__device__ inline void newton1_step(const float* __restrict__ Sig, float rTr,
                                    float* __restrict__ Pout, int rg0, int t,
                                    float* s1, float* s2, float* red) {
  const int ct = t & 31;
  const int rt = (t >> 5) & 1;
  const int kt = t >> 6;
  const int ra = rg0 + 4 * rt;
  const float nh = -0.5f * rTr;
  float a[4][4];

  // phase 1: s1 = strip(P1 @ P1)
#pragma unroll
  for (int i = 0; i < 4; ++i)
#pragma unroll
    for (int j = 0; j < 4; ++j) a[i][j] = 0.f;
#pragma unroll 4
  for (int k = kt * 32; k < kt * 32 + 32; ++k) {
    const float4 sa4 = *(const float4*)(Sig + k * 128 + ra);   // symmetry
    const float4 sb4 = *(const float4*)(Sig + k * 128 + 4 * ct);
    float aA[4] = {nh * sa4.x, nh * sa4.y, nh * sa4.z, nh * sa4.w};
    float bA[4] = {nh * sb4.x, nh * sb4.y, nh * sb4.z, nh * sb4.w};
#pragma unroll
    for (int i = 0; i < 4; ++i) if (ra + i == k) aA[i] += 1.5f;
#pragma unroll
    for (int j = 0; j < 4; ++j) if (4 * ct + j == k) bA[j] += 1.5f;
#pragma unroll
    for (int i = 0; i < 4; ++i)
#pragma unroll
      for (int j = 0; j < 4; ++j) a[i][j] += aA[i] * bA[j];
  }
#pragma unroll
  for (int i = 0; i < 4; ++i)
#pragma unroll
    for (int j = 0; j < 4; ++j) red[t * 17 + i * 4 + j] = a[i][j];
  __syncthreads();
  if (t < 64) {
#pragma unroll
    for (int u = 1; u < 4; ++u)
#pragma unroll
      for (int i = 0; i < 4; ++i)
#pragma unroll
        for (int j = 0; j < 4; ++j)
          a[i][j] += red[(t + 64 * u) * 17 + i * 4 + j];
#pragma unroll
    for (int i = 0; i < 4; ++i)
#pragma unroll
      for (int j = 0; j < 4; ++j)
        s1[(4 * rt + i) * 132 + 4 * ct + j] = a[i][j];
  }
  __syncthreads();

  // phase 2: s2 = s1 @ P1
#pragma unroll
  for (int i = 0; i < 4; ++i)
#pragma unroll
    for (int j = 0; j < 4; ++j) a[i][j] = 0.f;
#pragma unroll 4
  for (int k = kt * 32; k < kt * 32 + 32; ++k) {
    float aA[4];
#pragma unroll
    for (int i = 0; i < 4; ++i) aA[i] = s1[(4 * rt + i) * 132 + k];
    const float4 sb4 = *(const float4*)(Sig + k * 128 + 4 * ct);
    float bA[4] = {nh * sb4.x, nh * sb4.y, nh * sb4.z, nh * sb4.w};
#pragma unroll
    for (int j = 0; j < 4; ++j) if (4 * ct + j == k) bA[j] += 1.5f;
#pragma unroll
    for (int i = 0; i < 4; ++i)
#pragma unroll
      for (int j = 0; j < 4; ++j) a[i][j] += aA[i] * bA[j];
  }
  __syncthreads();
#pragma unroll
  for (int i = 0; i < 4; ++i)
#pragma unroll
    for (int j = 0; j < 4; ++j) red[t * 17 + i * 4 + j] = a[i][j];
  __syncthreads();
  if (t < 64) {
#pragma unroll
    for (int u = 1; u < 4; ++u)
#pragma unroll
      for (int i = 0; i < 4; ++i)
#pragma unroll
        for (int j = 0; j < 4; ++j)
          a[i][j] += red[(t + 64 * u) * 17 + i * 4 + j];
#pragma unroll
    for (int i = 0; i < 4; ++i)
#pragma unroll
      for (int j = 0; j < 4; ++j)
        s2[(4 * rt + i) * 132 + 4 * ct + j] = a[i][j];
  }
  __syncthreads();

  // phase 3: a = s2 @ Sigma_raw; Pout = 0.5*(3 P1 - rTr*a)
#pragma unroll
  for (int i = 0; i < 4; ++i)
#pragma unroll
    for (int j = 0; j < 4; ++j) a[i][j] = 0.f;
#pragma unroll 4
  for (int k = kt * 32; k < kt * 32 + 32; ++k) {
    float aA[4];
#pragma unroll
    for (int i = 0; i < 4; ++i) aA[i] = s2[(4 * rt + i) * 132 + k];
    const float4 bv = *(const float4*)(Sig + k * 128 + 4 * ct);
    const float bA[4] = {bv.x, bv.y, bv.z, bv.w};
#pragma unroll
    for (int i = 0; i < 4; ++i)
#pragma unroll
      for (int j = 0; j < 4; ++j) a[i][j] += aA[i] * bA[j];
  }
  __syncthreads();
#pragma unroll
  for (int i = 0; i < 4; ++i)
#pragma unroll
    for (int j = 0; j < 4; ++j) red[t * 17 + i * 4 + j] = a[i][j];
  __syncthreads();
  if (t < 64) {
#pragma unroll
    for (int u = 1; u < 4; ++u)
#pragma unroll
      for (int i = 0; i < 4; ++i)
#pragma unroll
        for (int j = 0; j < 4; ++j)
          a[i][j] += red[(t + 64 * u) * 17 + i * 4 + j];
#pragma unroll
    for (int i = 0; i < 4; ++i) {
      const int rg = rg0 + 4 * rt + i;
      const float4 sv = *(const float4*)(Sig + rg * 128 + 4 * ct);
      float p1v[4] = {nh * sv.x, nh * sv.y, nh * sv.z, nh * sv.w};
#pragma unroll
      for (int j = 0; j < 4; ++j) if (4 * ct + j == rg) p1v[j] += 1.5f;
      *(float4*)(Pout + rg * 128 + 4 * ct) =
          make_float4(0.5f * (3.f * p1v[0] - rTr * a[i][0]),
                      0.5f * (3.f * p1v[1] - rTr * a[i][1]),
                      0.5f * (3.f * p1v[2] - rTr * a[i][2]),
                      0.5f * (3.f * p1v[3] - rTr * a[i][3]));
    }
  }
}

// ---------------------------------------------------------------------------
// Kernel 2 (fused mid-chain): S-reduce -> Sigma-build -> 4 Newton steps ->
// rot@P + bias. grid = 128 x 256 (co-resident), 6 grid barriers replace 5
// kernel launches. Each Newton writes a DISTINCT buffer (no read-after-
// rewrite within the launch -> no stale-L1 hazard).
// ---------------------------------------------------------------------------
__global__ __launch_bounds__(256) void mid_k(
    const float* __restrict__ partG, const float* __restrict__ partS,
    const float* __restrict__ rot, float* __restrict__ Sigma,
    float* __restrict__ Pa, float* __restrict__ Pb, float* __restrict__ Pc,
    float* __restrict__ Pd, float* __restrict__ S, float* __restrict__ trace,
    unsigned* __restrict__ ctr, unsigned short* __restrict__ Mbf,
    float* __restrict__ bias, int slots) {
  __shared__ float s1[8 * 132];
  __shared__ float s2[8 * 132];
  __shared__ __align__(16) float red[256 * 17];
  const int t = threadIdx.x;
  const int b = blockIdx.x;
  const unsigned NB = gridDim.x;

  // ---- phase A: S[b] = sum_slots partS ----
  {
    float sa = 0.f;
    for (int s = t; s < slots; s += 256) sa += partS[(size_t)s * 128 + b];
    red[t] = sa;
    __syncthreads();
    for (int off = 128; off > 0; off >>= 1) {
      if (t < off) red[t] += red[t + off];
      __syncthreads();
    }
    if (t == 0) S[b] = red[0];
  }
  gbar(&ctr[0], NB);

  // ---- phase B: Sigma row b = (G - S S^T/m)/m + eps*I; trace partial ----
  {
    float4* red4 = (float4*)red;
    const int q = t & 31;
    const int h = t >> 5;
    const float* base = partG + (size_t)b * 128 + 4 * q;
    float ax = 0.f, ay = 0.f, az = 0.f, aw = 0.f;
#pragma unroll 8
    for (int s = h; s < slots; s += 8) {
      const float4 v = *(const float4*)(base + (size_t)s * 16384);
      ax += v.x; ay += v.y; az += v.z; aw += v.w;
    }
    red4[t] = make_float4(ax, ay, az, aw);
    __syncthreads();
    if (t < 128) {
      const float4 o = red4[t + 128];
      red4[t].x += o.x; red4[t].y += o.y; red4[t].z += o.z; red4[t].w += o.w;
    }
    __syncthreads();
    if (t < 64) {
      const float4 o = red4[t + 64];
      red4[t].x += o.x; red4[t].y += o.y; red4[t].z += o.z; red4[t].w += o.w;
    }
    __syncthreads();
    if (t < 32) {
      const float4 g0 = red4[t];
      const float4 g1 = red4[t + 32];
      const float rm = 1.0f / M_TOT;
      const float sb = S[b] * rm;
      const float4 s4 = *(const float4*)(S + 4 * t);
      float o[4];
      o[0] = (g0.x + g1.x - sb * s4.x) * rm;
      o[1] = (g0.y + g1.y - sb * s4.y) * rm;
      o[2] = (g0.z + g1.z - sb * s4.z) * rm;
      o[3] = (g0.w + g1.w - sb * s4.w) * rm;
      if (t == (b >> 2)) {
        o[b & 3] += EPSV;
        atomicAdd(trace, o[b & 3]);
      }
      *(float4*)(Sigma + b * 128 + 4 * t) = make_float4(o[0], o[1], o[2], o[3]);
    }
  }
  gbar(&ctr[1], NB);

  const float rTr = 1.0f / *trace;

  // ---- phases C-F: Newton chain on blocks 0..15 ----
  if (b < 16) newton1_step(Sigma, rTr, Pa, b * 8, t, s1, s2, red);   // P2
  gbar(&ctr[2], NB);
  if (b < 16) newton_step(Pa, Sigma, rTr, Pb, b * 8, t, s1, s2, red); // P3
  gbar(&ctr[3], NB);
  if (b < 16) newton_step(Pb, Sigma, rTr, Pc, b * 8, t, s1, s2, red); // P4
  gbar(&ctr[4], NB);
  if (b < 16) newton_step(Pc, Sigma, rTr, Pd, b * 8, t, s1, s2, red); // P5
  gbar(&ctr[5], NB);

  // ---- phase G: M row b = sqrt(rTr) * rot[b] @ P5; bias[b] = M[b].mean ----
  {
    if (t < 128) s1[t] = rot[b * 128 + t];
    __syncthreads();
    const float sc = sqrtf(rTr);
    const int c = t & 127;
    const int kh = t >> 7;
    float a = 0.f;
#pragma unroll 4
    for (int k = kh * 64; k < kh * 64 + 64; ++k)
      a += s1[k] * Pd[(size_t)k * 128 + c];
    s2[t] = a;
    __syncthreads();
    if (t < 128) {
      const float m = (s2[t] + s2[t + 128]) * sc;
      Mbf[b * 128 + t] = f2bf(m);
      s2[t] = m * S[t];
    }
    __syncthreads();
    for (int off = 64; off > 0; off >>= 1) {
      if (t < off) s2[t] += s2[t + off];
      __syncthreads();
    }
    if (t == 0) bias[b] = s2[0] * (1.0f / M_TOT);
  }
}

// ---------------------------------------------------------------------------
// Kernel 3: out[b,d,s] = sum_c M[d][c]*x[c,s] - bias[d], bf16 MFMA.
// grid = 3136, block = 256 (4 waves), 3 blocks/CU.
// ---------------------------------------------------------------------------
#define MSTR 136
#define XSTR 132
__global__ __launch_bounds__(256, 3) void apply_k(const float* __restrict__ x,
                                                  const unsigned short* __restrict__ Mbf,
                                                  const float* __restrict__ bias,
                                                  float* __restrict__ out) {
  __shared__ unsigned short Ms[128 * MSTR];   // 34816 B
  __shared__ unsigned short xsB[64 * XSTR];   // 16896 B
  const int t = threadIdx.x;
  const int lm = t & 15, quad = (t >> 4) & 3, w = t >> 6;
  const int b = blockIdx.x / 49;
  const int s0 = (blockIdx.x % 49) * 64;

  // stage M (L2-hot) -- independent of x loads, overlaps them
#pragma unroll
  for (int i = 0; i < 8; ++i) {
    const int e = i * 256 + t;
    const int row = e >> 4, oct = e & 15;
    *(uint4*)&Ms[row * MSTR + oct * 8] =
        *(const uint4*)(Mbf + row * 128 + oct * 8);
  }
  // stage x chunk transposed: pair p -> channels {2p, 2p+1}
#pragma unroll
  for (int i = 0; i < 4; ++i) {
    const int p = 16 * i + (t >> 4);
    const int q = t & 15;
    const float* px = x + (size_t)(b * 128 + 2 * p) * HW + s0 + 4 * q;
    const float4 fa = *(const float4*)px;
    const float4 fb = *(const float4*)(px + HW);
    const float faA[4] = {fa.x, fa.y, fa.z, fa.w};
    const float fbA[4] = {fb.x, fb.y, fb.z, fb.w};
#pragma unroll
    for (int r = 0; r < 4; ++r) {
      const unsigned dw =
          (unsigned)f2bf(faA[r]) | ((unsigned)f2bf(fbA[r]) << 16);
      *(unsigned*)&xsB[(4 * q + r) * XSTR + 2 * p] = dw;
    }
  }
  float biasr[2][4];
#pragma unroll
  for (int i = 0; i < 2; ++i)
#pragma unroll
    for (int r = 0; r < 4; ++r)
      biasr[i][r] = bias[(2 * w + i) * 16 + quad * 4 + r];
  __syncthreads();

  const f32x4 z = {0.f, 0.f, 0.f, 0.f};
  f32x4 acc[2][4];
#pragma unroll
  for (int i = 0; i < 2; ++i)
#pragma unroll
    for (int sj = 0; sj < 4; ++sj) acc[i][sj] = z;

#pragma unroll
  for (int ks = 0; ks < 4; ++ks) {
    const int ko = ks * 32 + quad * 8;
    const bf16x8 a0 = *(const bf16x8*)&Ms[((2 * w + 0) * 16 + lm) * MSTR + ko];
    const bf16x8 a1 = *(const bf16x8*)&Ms[((2 * w + 1) * 16 + lm) * MSTR + ko];
#pragma unroll
    for (int sj = 0; sj < 4; ++sj) {
      const short4v blo = *(const short4v*)&xsB[(sj * 16 + lm) * XSTR + ko];
      const short4v bhi = *(const short4v*)&xsB[(sj * 16 + lm) * XSTR + ko + 4];
      const bf16x8 bf = __builtin_shufflevector(blo, bhi, 0, 1, 2, 3, 4, 5, 6, 7);
      acc[0][sj] = __builtin_amdgcn_mfma_f32_16x16x32_bf16(a0, bf, acc[0][sj], 0, 0, 0);
      acc[1][sj] = __builtin_amdgcn_mfma_f32_16x16x32_bf16(a1, bf, acc[1][sj], 0, 0, 0);
    }
  }
  // epilogue: D col = lane&15 = s, row = quad*4+reg = d-within-tile
#pragma unroll
  for (int i = 0; i < 2; ++i)
#pragma unroll
    for (int r = 0; r < 4; ++r) {
      const int d = (2 * w + i) * 16 + quad * 4 + r;
      float* orow = out + (size_t)(b * 128 + d) * HW + s0 + lm;
#pragma unroll
      for (int sj = 0; sj < 4; ++sj)
        orow[sj * 16] = acc[i][sj][r] - biasr[i][r];
    }
}

// ---------------------------------------------------------------------------
extern "C" void kernel_launch(void* const* d_in, const int* in_sizes, int n_in,
                              void* d_out, int out_size, void* d_ws,
                              size_t ws_size, hipStream_t stream) {
  const float* x = (const float*)d_in[0];        // (64,128,56,56) fp32
  const float* rot = (const float*)d_in[1];      // (128,128) fp32
  float* out = (float*)d_out;                    // (64,128,56,56) fp32
  float* ws = (float*)d_ws;

  // ws layout (floats)
  float* Sigma  = ws;                        // 16384 (raw, eps included)
  float* Pa     = ws + 16384;                // 16384
  float* Pb     = ws + 32768;                // 16384
  float* Pc     = ws + 49152;                // 16384
  float* Pd     = ws + 65536;                // 16384
  unsigned short* Mbf = (unsigned short*)(ws + 81920);  // 16384 ushort
  float* S      = ws + 90112;                // 128
  float* bias   = ws + 90240;                // 128
  float* trace  = ws + 90368;                // 1
  unsigned* ctr = (unsigned*)(ws + 90369);   // 8 barrier counters
  float* partG  = ws + 90384;

  const size_t wsf = ws_size / 4;
  long avail = (long)wsf - 90384;
  int slots = (int)(avail / (16384 + 128));
  if (slots > 512) slots = 512;
  if (slots < 1) slots = 1;
  float* partS = partG + (size_t)slots * 16384;

  hipMemsetAsync(trace, 0, 9 * 4, stream);  // zero trace + 8 barrier counters

  gram_k<<<slots, 512, 0, stream>>>(x, partG, partS, slots);
  mid_k<<<128, 256, 0, stream>>>(partG, partS, rot, Sigma, Pa, Pb, Pc, Pd, S,
                                 trace, ctr, Mbf, bias, slots);
  apply_k<<<3136, 256, 0, stream>>>(x, Mbf, bias, out);
}

// Round 3
// 265.618 us; speedup vs baseline: 1.5414x; 1.5414x over previous
//
#include <hip/hip_runtime.h>
#include <math.h>

// Problem constants (B=64, C=128, H=W=56)
#define HW 3136
#define NCHUNK 3136          // 64 batches * 49 chunks of 64 samples
#define M_TOT 200704.0f
#define EPSV 1e-5f

typedef __attribute__((ext_vector_type(8))) short bf16x8;
typedef __attribute__((ext_vector_type(4))) short short4v;
typedef __attribute__((ext_vector_type(4))) float f32x4;

__device__ inline unsigned short f2bf(float f) {  // RNE fp32->bf16
  unsigned u = __float_as_uint(f);
  u += 0x7FFFu + ((u >> 16) & 1u);
  return (unsigned short)(u >> 16);
}

// ---------------------------------------------------------------------------
// Kernel 1: partial Gram (X @ X^T) + channel sums, bf16 MFMA 16x16x32.
// grid = slots (512), block = 512 (8 waves -> 16 waves/CU at 2 blocks/CU).
// TWO-DEEP VGPR prefetch + double-buffered LDS, ONE barrier per iteration.
// (Round-1 evidence: VALU 4.8% / MFMA 3.1% / HBM 12% -> pure load-latency
// stall; 1-deep prefetch gave each load <1 compute phase to complete. 2-deep
// gives ~2 full iterations.) partS plain stores (atomicAdd to S[128] was a
// ~30us serialization tail). D layout (m89): col = lane&15, row = quad*4+reg.
// ---------------------------------------------------------------------------
__global__ __launch_bounds__(512, 4) void gram_k(const float* __restrict__ x,
                                                 float* __restrict__ partG,
                                                 float* __restrict__ partS,
                                                 int slots) {
  __shared__ unsigned short xs[2][128 * 72];  // 2 x 18432 B
  const int t = threadIdx.x;
  const int lm = t & 15, quad = (t >> 4) & 3, w = t >> 6;  // w = 0..7
  const int row0 = w * 16;
  const int qofs = (t & 15) * 4;   // sample-quad offset for staging
  const int chi = t >> 4;          // 0..31 channel sub-index for staging

  f32x4 acc[8];
  f32x4 sacc;
  const f32x4 z = {0.f, 0.f, 0.f, 0.f};
  sacc = z;
#pragma unroll
  for (int j = 0; j < 8; ++j) acc[j] = z;
  bf16x8 ones;
#pragma unroll
  for (int j = 0; j < 8; ++j) ones[j] = (short)0x3F80;  // bf16 1.0

  int chunk = blockIdx.x;
  float4 pre0[4], pre1[4];
  {
    const int b = chunk / 49;
    const int s0 = (chunk % 49) * 64;
    const float* base = x + (size_t)(b * 128) * HW + s0;
#pragma unroll
    for (int i = 0; i < 4; ++i)
      pre0[i] = *(const float4*)(base + (size_t)(i * 32 + chi) * HW + qofs);
  }
  {
    const int n1 = chunk + slots;
    if (n1 < NCHUNK) {
      const int b = n1 / 49;
      const int s0 = (n1 % 49) * 64;
      const float* base = x + (size_t)(b * 128) * HW + s0;
#pragma unroll
      for (int i = 0; i < 4; ++i)
        pre1[i] = *(const float4*)(base + (size_t)(i * 32 + chi) * HW + qofs);
    }
  }

  int buf = 0;
  while (chunk < NCHUNK) {
    // stage pre0 (chunk) -> xs[buf]
#pragma unroll
    for (int i = 0; i < 4; ++i) {
      const int c = i * 32 + chi;
      uint2 dw;
      dw.x = (unsigned)f2bf(pre0[i].x) | ((unsigned)f2bf(pre0[i].y) << 16);
      dw.y = (unsigned)f2bf(pre0[i].z) | ((unsigned)f2bf(pre0[i].w) << 16);
      *(uint2*)&xs[buf][c * 72 + qofs] = dw;
    }
    __syncthreads();
    // rotate pipeline: pre0 <- pre1, issue pre1 <- chunk+2*slots
#pragma unroll
    for (int i = 0; i < 4; ++i) pre0[i] = pre1[i];
    {
      const int n2 = chunk + 2 * slots;
      if (n2 < NCHUNK) {
        const int b = n2 / 49;
        const int s0 = (n2 % 49) * 64;
        const float* base = x + (size_t)(b * 128) * HW + s0;
#pragma unroll
        for (int i = 0; i < 4; ++i)
          pre1[i] = *(const float4*)(base + (size_t)(i * 32 + chi) * HW + qofs);
      }
    }
    // compute from xs[buf]
#pragma unroll
    for (int ks = 0; ks < 2; ++ks) {
      const int ko = ks * 32 + quad * 8;
      const bf16x8 a0 = *(const bf16x8*)&xs[buf][(row0 + lm) * 72 + ko];
      sacc = __builtin_amdgcn_mfma_f32_16x16x32_bf16(a0, ones, sacc, 0, 0, 0);
#pragma unroll
      for (int tj = 0; tj < 8; ++tj) {
        const bf16x8 bf = *(const bf16x8*)&xs[buf][(tj * 16 + lm) * 72 + ko];
        acc[tj] = __builtin_amdgcn_mfma_f32_16x16x32_bf16(a0, bf, acc[tj], 0, 0, 0);
      }
    }
    buf ^= 1;
    chunk += slots;
  }

  float* pg = partG + (size_t)blockIdx.x * 16384;
#pragma unroll
  for (int tj = 0; tj < 8; ++tj)
#pragma unroll
    for (int r = 0; r < 4; ++r)
      pg[(row0 + quad * 4 + r) * 128 + tj * 16 + lm] = acc[tj][r];
  if (lm == 0) {
#pragma unroll
    for (int r = 0; r < 4; ++r)
      partS[blockIdx.x * 128 + row0 + quad * 4 + r] = sacc[r];
  }
}

// ---------------------------------------------------------------------------
// Kernel 2: stage-A reduction (32 slot-groups x 16 elem-groups = 512 blocks).
// ---------------------------------------------------------------------------
__global__ __launch_bounds__(256) void reduce1_k(const float* __restrict__ partG,
                                                 const float* __restrict__ partS,
                                                 float* __restrict__ part2,
                                                 float* __restrict__ part2S,
                                                 int slots) {
  const int t = threadIdx.x;
  const int sg = blockIdx.x & 31;
  const int eg = blockIdx.x >> 5;
  const int e4 = eg * 1024 + t * 4;
  float ax = 0.f, ay = 0.f, az = 0.f, aw = 0.f;
#pragma unroll 4
  for (int s = sg; s < slots; s += 32) {
    const float4 v = *(const float4*)(partG + (size_t)s * 16384 + e4);
    ax += v.x; ay += v.y; az += v.z; aw += v.w;
  }
  *(float4*)(part2 + (size_t)sg * 16384 + e4) = make_float4(ax, ay, az, aw);
  if (eg == 0 && t < 128) {
    float sa = 0.f;
    for (int s = sg; s < slots; s += 32) sa += partS[s * 128 + t];
    part2S[sg * 128 + t] = sa;
  }
}

// ---------------------------------------------------------------------------
// Kernel 3: merged stage-B reduce + Sigma build. grid = 16, block = 256.
// Raw Sigma = (G - S S^T/m)/m + eps*I (trace normalization deferred via
// traceP[0..15] partials).
// ---------------------------------------------------------------------------
__global__ __launch_bounds__(256) void sigred_k(const float* __restrict__ part2,
                                                const float* __restrict__ part2S,
                                                float* __restrict__ Sigma,
                                                float* __restrict__ traceP,
                                                float* __restrict__ meanOut) {
  __shared__ float SbL[128];
  __shared__ float red[256];
  const int t = threadIdx.x;
  if (t < 128) {
    float sa = 0.f;
#pragma unroll
    for (int sg = 0; sg < 32; ++sg) sa += part2S[sg * 128 + t];
    SbL[t] = sa;
    if (blockIdx.x == 0) meanOut[t] = sa * (1.0f / M_TOT);
  }
  __syncthreads();
  const int e4 = blockIdx.x * 1024 + t * 4;
  float ax = 0.f, ay = 0.f, az = 0.f, aw = 0.f;
#pragma unroll
  for (int sg = 0; sg < 32; ++sg) {
    const float4 v = *(const float4*)(part2 + (size_t)sg * 16384 + e4);
    ax += v.x; ay += v.y; az += v.z; aw += v.w;
  }
  const int r = e4 >> 7, c0 = e4 & 127;
  const float rm = 1.0f / M_TOT;
  const float sr = SbL[r] * rm;
  float s4[4];
  s4[0] = (ax - sr * SbL[c0 + 0]) * rm;
  s4[1] = (ay - sr * SbL[c0 + 1]) * rm;
  s4[2] = (az - sr * SbL[c0 + 2]) * rm;
  s4[3] = (aw - sr * SbL[c0 + 3]) * rm;
  float trl = 0.f;
#pragma unroll
  for (int j = 0; j < 4; ++j) {
    if (c0 + j == r) { s4[j] += EPSV; trl = s4[j]; }
  }
  *(float4*)(Sigma + e4) = make_float4(s4[0], s4[1], s4[2], s4[3]);
  red[t] = trl;
  __syncthreads();
  for (int off = 128; off > 0; off >>= 1) {
    if (t < off) red[t] += red[t + off];
    __syncthreads();
  }
  if (t == 0) traceP[blockIdx.x] = red[0];
}

// ---------------------------------------------------------------------------
// Kernel 4a: FIRST+SECOND Newton step fused (P1 = 1.5I - 0.5*rTr*Sigma
// synthesized; computes P2). grid = 16, block = 256. 4x4 tile, 4-way K-split.
// ---------------------------------------------------------------------------
__global__ __launch_bounds__(256) void newton1_k(const float* __restrict__ Sig,
                                                 const float* __restrict__ traceP,
                                                 float* __restrict__ Pout) {
  __shared__ float s1[8 * 132];
  __shared__ float s2[8 * 132];
  __shared__ float red[256 * 17];
  const int t = threadIdx.x;
  const int ct = t & 31;
  const int rt = (t >> 5) & 1;
  const int kt = t >> 6;
  const int rg0 = blockIdx.x * 8;
  const int ra = rg0 + 4 * rt;
  float tr = 0.f;
#pragma unroll
  for (int i = 0; i < 16; ++i) tr += traceP[i];
  const float rTr = 1.0f / tr;
  const float nh = -0.5f * rTr;
  float a[4][4];

  // ---------- phase 1: s1 = strip(P1 @ P1) ----------
#pragma unroll
  for (int i = 0; i < 4; ++i)
#pragma unroll
    for (int j = 0; j < 4; ++j) a[i][j] = 0.f;
#pragma unroll 4
  for (int k = kt * 32; k < kt * 32 + 32; ++k) {
    const float4 sa4 = *(const float4*)(Sig + k * 128 + ra);   // symmetry
    const float4 sb4 = *(const float4*)(Sig + k * 128 + 4 * ct);
    float aA[4] = {nh * sa4.x, nh * sa4.y, nh * sa4.z, nh * sa4.w};
    float bA[4] = {nh * sb4.x, nh * sb4.y, nh * sb4.z, nh * sb4.w};
#pragma unroll
    for (int i = 0; i < 4; ++i) if (ra + i == k) aA[i] += 1.5f;
#pragma unroll
    for (int j = 0; j < 4; ++j) if (4 * ct + j == k) bA[j] += 1.5f;
#pragma unroll
    for (int i = 0; i < 4; ++i)
#pragma unroll
      for (int j = 0; j < 4; ++j) a[i][j] += aA[i] * bA[j];
  }
#pragma unroll
  for (int i = 0; i < 4; ++i)
#pragma unroll
    for (int j = 0; j < 4; ++j) red[t * 17 + i * 4 + j] = a[i][j];
  __syncthreads();
  if (t < 64) {
#pragma unroll
    for (int u = 1; u < 4; ++u)
#pragma unroll
      for (int i = 0; i < 4; ++i)
#pragma unroll
        for (int j = 0; j < 4; ++j)
          a[i][j] += red[(t + 64 * u) * 17 + i * 4 + j];
#pragma unroll
    for (int i = 0; i < 4; ++i)
#pragma unroll
      for (int j = 0; j < 4; ++j)
        s1[(4 * rt + i) * 132 + 4 * ct + j] = a[i][j];
  }
  __syncthreads();

  // ---------- phase 2: s2 = s1 @ P1 ----------
#pragma unroll
  for (int i = 0; i < 4; ++i)
#pragma unroll
    for (int j = 0; j < 4; ++j) a[i][j] = 0.f;
#pragma unroll 4
  for (int k = kt * 32; k < kt * 32 + 32; ++k) {
    float aA[4];
#pragma unroll
    for (int i = 0; i < 4; ++i) aA[i] = s1[(4 * rt + i) * 132 + k];
    const float4 sb4 = *(const float4*)(Sig + k * 128 + 4 * ct);
    float bA[4] = {nh * sb4.x, nh * sb4.y, nh * sb4.z, nh * sb4.w};
#pragma unroll
    for (int j = 0; j < 4; ++j) if (4 * ct + j == k) bA[j] += 1.5f;
#pragma unroll
    for (int i = 0; i < 4; ++i)
#pragma unroll
      for (int j = 0; j < 4; ++j) a[i][j] += aA[i] * bA[j];
  }
  __syncthreads();
#pragma unroll
  for (int i = 0; i < 4; ++i)
#pragma unroll
    for (int j = 0; j < 4; ++j) red[t * 17 + i * 4 + j] = a[i][j];
  __syncthreads();
  if (t < 64) {
#pragma unroll
    for (int u = 1; u < 4; ++u)
#pragma unroll
      for (int i = 0; i < 4; ++i)
#pragma unroll
        for (int j = 0; j < 4; ++j)
          a[i][j] += red[(t + 64 * u) * 17 + i * 4 + j];
#pragma unroll
    for (int i = 0; i < 4; ++i)
#pragma unroll
      for (int j = 0; j < 4; ++j)
        s2[(4 * rt + i) * 132 + 4 * ct + j] = a[i][j];
  }
  __syncthreads();

  // ---------- phase 3: a = s2 @ Sigma_raw; Pout = 0.5*(3 P1 - rTr*a) ----------
#pragma unroll
  for (int i = 0; i < 4; ++i)
#pragma unroll
    for (int j = 0; j < 4; ++j) a[i][j] = 0.f;
#pragma unroll 4
  for (int k = kt * 32; k < kt * 32 + 32; ++k) {
    float aA[4];
#pragma unroll
    for (int i = 0; i < 4; ++i) aA[i] = s2[(4 * rt + i) * 132 + k];
    const float4 bv = *(const float4*)(Sig + k * 128 + 4 * ct);
    const float bA[4] = {bv.x, bv.y, bv.z, bv.w};
#pragma unroll
    for (int i = 0; i < 4; ++i)
#pragma unroll
      for (int j = 0; j < 4; ++j) a[i][j] += aA[i] * bA[j];
  }
  __syncthreads();
#pragma unroll
  for (int i = 0; i < 4; ++i)
#pragma unroll
    for (int j = 0; j < 4; ++j) red[t * 17 + i * 4 + j] = a[i][j];
  __syncthreads();
  if (t < 64) {
#pragma unroll
    for (int u = 1; u < 4; ++u)
#pragma unroll
      for (int i = 0; i < 4; ++i)
#pragma unroll
        for (int j = 0; j < 4; ++j)
          a[i][j] += red[(t + 64 * u) * 17 + i * 4 + j];
#pragma unroll
    for (int i = 0; i < 4; ++i) {
      const int rg = rg0 + 4 * rt + i;
      const float4 sv = *(const float4*)(Sig + rg * 128 + 4 * ct);
      float p1v[4] = {nh * sv.x, nh * sv.y, nh * sv.z, nh * sv.w};
#pragma unroll
      for (int j = 0; j < 4; ++j) if (4 * ct + j == rg) p1v[j] += 1.5f;
      *(float4*)(Pout + rg * 128 + 4 * ct) =
          make_float4(0.5f * (3.f * p1v[0] - rTr * a[i][0]),
                      0.5f * (3.f * p1v[1] - rTr * a[i][1]),
                      0.5f * (3.f * p1v[2] - rTr * a[i][2]),
                      0.5f * (3.f * p1v[3] - rTr * a[i][3]));
    }
  }
}

// ---------------------------------------------------------------------------
// Kernel 4b: one Newton iteration: Pout = 0.5*(3P - ((P@P)@P)@(rTr*Sigma)).
// grid = 16, block = 256. P from global (symmetric).
// ---------------------------------------------------------------------------
__global__ __launch_bounds__(256) void newton_k(const float* __restrict__ P,
                                                const float* __restrict__ Sig,
                                                const float* __restrict__ traceP,
                                                float* __restrict__ Pout) {
  __shared__ float s1[8 * 132];
  __shared__ float s2[8 * 132];
  __shared__ float red[256 * 17];
  const int t = threadIdx.x;
  const int ct = t & 31;
  const int rt = (t >> 5) & 1;
  const int kt = t >> 6;
  const int rg0 = blockIdx.x * 8;
  float tr = 0.f;
#pragma unroll
  for (int i = 0; i < 16; ++i) tr += traceP[i];
  const float rTr = 1.0f / tr;
  float a[4][4];

  // ---------- phase 1: s1 = strip(P @ P) ----------
#pragma unroll
  for (int i = 0; i < 4; ++i)
#pragma unroll
    for (int j = 0; j < 4; ++j) a[i][j] = 0.f;
#pragma unroll 4
  for (int k = kt * 32; k < kt * 32 + 32; ++k) {
    const float4 av = *(const float4*)(P + k * 128 + rg0 + 4 * rt);  // symmetry
    const float4 bv = *(const float4*)(P + k * 128 + 4 * ct);
    const float aA[4] = {av.x, av.y, av.z, av.w};
    const float bA[4] = {bv.x, bv.y, bv.z, bv.w};
#pragma unroll
    for (int i = 0; i < 4; ++i)
#pragma unroll
      for (int j = 0; j < 4; ++j) a[i][j] += aA[i] * bA[j];
  }
#pragma unroll
  for (int i = 0; i < 4; ++i)
#pragma unroll
    for (int j = 0; j < 4; ++j) red[t * 17 + i * 4 + j] = a[i][j];
  __syncthreads();
  if (t < 64) {
#pragma unroll
    for (int u = 1; u < 4; ++u)
#pragma unroll
      for (int i = 0; i < 4; ++i)
#pragma unroll
        for (int j = 0; j < 4; ++j)
          a[i][j] += red[(t + 64 * u) * 17 + i * 4 + j];
#pragma unroll
    for (int i = 0; i < 4; ++i)
#pragma unroll
      for (int j = 0; j < 4; ++j)
        s1[(4 * rt + i) * 132 + 4 * ct + j] = a[i][j];
  }
  __syncthreads();

  // ---------- phase 2: s2 = s1 @ P ----------
#pragma unroll
  for (int i = 0; i < 4; ++i)
#pragma unroll
    for (int j = 0; j < 4; ++j) a[i][j] = 0.f;
#pragma unroll 4
  for (int k = kt * 32; k < kt * 32 + 32; ++k) {
    float aA[4];
#pragma unroll
    for (int i = 0; i < 4; ++i) aA[i] = s1[(4 * rt + i) * 132 + k];
    const float4 bv = *(const float4*)(P + k * 128 + 4 * ct);
    const float bA[4] = {bv.x, bv.y, bv.z, bv.w};
#pragma unroll
    for (int i = 0; i < 4; ++i)
#pragma unroll
      for (int j = 0; j < 4; ++j) a[i][j] += aA[i] * bA[j];
  }
  __syncthreads();
#pragma unroll
  for (int i = 0; i < 4; ++i)
#pragma unroll
    for (int j = 0; j < 4; ++j) red[t * 17 + i * 4 + j] = a[i][j];
  __syncthreads();
  if (t < 64) {
#pragma unroll
    for (int u = 1; u < 4; ++u)
#pragma unroll
      for (int i = 0; i < 4; ++i)
#pragma unroll
        for (int j = 0; j < 4; ++j)
          a[i][j] += red[(t + 64 * u) * 17 + i * 4 + j];
#pragma unroll
    for (int i = 0; i < 4; ++i)
#pragma unroll
      for (int j = 0; j < 4; ++j)
        s2[(4 * rt + i) * 132 + 4 * ct + j] = a[i][j];
  }
  __syncthreads();

  // ---------- phase 3: a = s2 @ Sigma_raw; Pout = 0.5*(3P - rTr*a) ----------
#pragma unroll
  for (int i = 0; i < 4; ++i)
#pragma unroll
    for (int j = 0; j < 4; ++j) a[i][j] = 0.f;
#pragma unroll 4
  for (int k = kt * 32; k < kt * 32 + 32; ++k) {
    float aA[4];
#pragma unroll
    for (int i = 0; i < 4; ++i) aA[i] = s2[(4 * rt + i) * 132 + k];
    const float4 bv = *(const float4*)(Sig + k * 128 + 4 * ct);
    const float bA[4] = {bv.x, bv.y, bv.z, bv.w};
#pragma unroll
    for (int i = 0; i < 4; ++i)
#pragma unroll
      for (int j = 0; j < 4; ++j) a[i][j] += aA[i] * bA[j];
  }
  __syncthreads();
#pragma unroll
  for (int i = 0; i < 4; ++i)
#pragma unroll
    for (int j = 0; j < 4; ++j) red[t * 17 + i * 4 + j] = a[i][j];
  __syncthreads();
  if (t < 64) {
#pragma unroll
    for (int u = 1; u < 4; ++u)
#pragma unroll
      for (int i = 0; i < 4; ++i)
#pragma unroll
        for (int j = 0; j < 4; ++j)
          a[i][j] += red[(t + 64 * u) * 17 + i * 4 + j];
#pragma unroll
    for (int i = 0; i < 4; ++i) {
      const int rg = rg0 + 4 * rt + i;
      const float4 pv = *(const float4*)(P + rg * 128 + 4 * ct);
      *(float4*)(Pout + rg * 128 + 4 * ct) =
          make_float4(0.5f * (3.f * pv.x - rTr * a[i][0]),
                      0.5f * (3.f * pv.y - rTr * a[i][1]),
                      0.5f * (3.f * pv.z - rTr * a[i][2]),
                      0.5f * (3.f * pv.w - rTr * a[i][3]));
    }
  }
}

// ---------------------------------------------------------------------------
// Kernel 5: Mbf = bf16(sqrt(rTr) * rot @ P) row-major [d][c];
// bias[d] = sum_c M[d][c]*mean[c]. grid = 16, block = 256.
// ---------------------------------------------------------------------------
__global__ __launch_bounds__(256) void rotmt_k(const float* __restrict__ rot,
                                               const float* __restrict__ P,
                                               const float* __restrict__ mean,
                                               const float* __restrict__ traceP,
                                               unsigned short* __restrict__ Mbf,
                                               float* __restrict__ bias) {
  const int t = threadIdx.x;
  const int r = t >> 5;
  const int dg = blockIdx.x * 8 + r;
  const int c0 = (t & 31) * 4;
  const float* rrow = rot + dg * 128;
  float tr = 0.f;
#pragma unroll
  for (int i = 0; i < 16; ++i) tr += traceP[i];
  const float sc = sqrtf(1.0f / tr);

  float ax = 0, ay = 0, az = 0, aw = 0;
#pragma unroll 4
  for (int k = 0; k < 128; ++k) {
    const float a = rrow[k];
    const float4 bv = *(const float4*)(P + k * 128 + c0);
    ax += a * bv.x; ay += a * bv.y; az += a * bv.z; aw += a * bv.w;
  }
  ax *= sc; ay *= sc; az *= sc; aw *= sc;
  uint2 dw;
  dw.x = (unsigned)f2bf(ax) | ((unsigned)f2bf(ay) << 16);
  dw.y = (unsigned)f2bf(az) | ((unsigned)f2bf(aw) << 16);
  *(uint2*)&Mbf[dg * 128 + c0] = dw;
  const float4 mv = *(const float4*)(mean + c0);
  float p = ax * mv.x + ay * mv.y + az * mv.z + aw * mv.w;
  for (int off = 16; off > 0; off >>= 1) p += __shfl_down(p, off, 32);
  if ((t & 31) == 0) bias[dg] = p;
}

// ---------------------------------------------------------------------------
// Kernel 6: out[b,d,s] = sum_c M[d][c]*x[c,s] - bias[d], bf16 MFMA.
// grid = 3136, block = 256 (4 waves), 3 blocks/CU (LDS 51.7KB x3 = 155KB).
// ---------------------------------------------------------------------------
#define MSTR 136
#define XSTR 132
__global__ __launch_bounds__(256, 3) void apply_k(const float* __restrict__ x,
                                                  const unsigned short* __restrict__ Mbf,
                                                  const float* __restrict__ bias,
                                                  float* __restrict__ out) {
  __shared__ unsigned short Ms[128 * MSTR];   // 34816 B
  __shared__ unsigned short xsB[64 * XSTR];   // 16896 B
  const int t = threadIdx.x;
  const int lm = t & 15, quad = (t >> 4) & 3, w = t >> 6;
  const int b = blockIdx.x / 49;
  const int s0 = (blockIdx.x % 49) * 64;

  // stage M (L2-hot) -- independent of x loads, overlaps them
#pragma unroll
  for (int i = 0; i < 8; ++i) {
    const int e = i * 256 + t;
    const int row = e >> 4, oct = e & 15;
    *(uint4*)&Ms[row * MSTR + oct * 8] =
        *(const uint4*)(Mbf + row * 128 + oct * 8);
  }
  // stage x chunk transposed: pair p -> channels {2p, 2p+1}
#pragma unroll
  for (int i = 0; i < 4; ++i) {
    const int p = 16 * i + (t >> 4);
    const int q = t & 15;
    const float* px = x + (size_t)(b * 128 + 2 * p) * HW + s0 + 4 * q;
    const float4 fa = *(const float4*)px;
    const float4 fb = *(const float4*)(px + HW);
    const float faA[4] = {fa.x, fa.y, fa.z, fa.w};
    const float fbA[4] = {fb.x, fb.y, fb.z, fb.w};
#pragma unroll
    for (int r = 0; r < 4; ++r) {
      const unsigned dw =
          (unsigned)f2bf(faA[r]) | ((unsigned)f2bf(fbA[r]) << 16);
      *(unsigned*)&xsB[(4 * q + r) * XSTR + 2 * p] = dw;
    }
  }
  float biasr[2][4];
#pragma unroll
  for (int i = 0; i < 2; ++i)
#pragma unroll
    for (int r = 0; r < 4; ++r)
      biasr[i][r] = bias[(2 * w + i) * 16 + quad * 4 + r];
  __syncthreads();

  const f32x4 z = {0.f, 0.f, 0.f, 0.f};
  f32x4 acc[2][4];
#pragma unroll
  for (int i = 0; i < 2; ++i)
#pragma unroll
    for (int sj = 0; sj < 4; ++sj) acc[i][sj] = z;

#pragma unroll
  for (int ks = 0; ks < 4; ++ks) {
    const int ko = ks * 32 + quad * 8;
    const bf16x8 a0 = *(const bf16x8*)&Ms[((2 * w + 0) * 16 + lm) * MSTR + ko];
    const bf16x8 a1 = *(const bf16x8*)&Ms[((2 * w + 1) * 16 + lm) * MSTR + ko];
#pragma unroll
    for (int sj = 0; sj < 4; ++sj) {
      const short4v blo = *(const short4v*)&xsB[(sj * 16 + lm) * XSTR + ko];
      const short4v bhi = *(const short4v*)&xsB[(sj * 16 + lm) * XSTR + ko + 4];
      const bf16x8 bf = __builtin_shufflevector(blo, bhi, 0, 1, 2, 3, 4, 5, 6, 7);
      acc[0][sj] = __builtin_amdgcn_mfma_f32_16x16x32_bf16(a0, bf, acc[0][sj], 0, 0, 0);
      acc[1][sj] = __builtin_amdgcn_mfma_f32_16x16x32_bf16(a1, bf, acc[1][sj], 0, 0, 0);
    }
  }
  // epilogue: D col = lane&15 = s, row = quad*4+reg = d-within-tile
#pragma unroll
  for (int i = 0; i < 2; ++i)
#pragma unroll
    for (int r = 0; r < 4; ++r) {
      const int d = (2 * w + i) * 16 + quad * 4 + r;
      float* orow = out + (size_t)(b * 128 + d) * HW + s0 + lm;
#pragma unroll
      for (int sj = 0; sj < 4; ++sj)
        orow[sj * 16] = acc[i][sj][r] - biasr[i][r];
    }
}

// ---------------------------------------------------------------------------
extern "C" void kernel_launch(void* const* d_in, const int* in_sizes, int n_in,
                              void* d_out, int out_size, void* d_ws,
                              size_t ws_size, hipStream_t stream) {
  const float* x = (const float*)d_in[0];        // (64,128,56,56) fp32
  const float* rot = (const float*)d_in[1];      // (128,128) fp32
  float* out = (float*)d_out;                    // (64,128,56,56) fp32
  float* ws = (float*)d_ws;

  // ws layout (floats)
  float* Sigma  = ws;                        // 16384 (raw, eps included)
  float* Pa     = ws + 16384;                // 16384
  float* Pb     = ws + 32768;                // 16384
  unsigned short* Mbf = (unsigned short*)(ws + 49152);  // 16384 ushort
  float* Sb     = ws + 57344;                // 128 (mean)
  float* bias   = ws + 57472;                // 128
  float* traceP = ws + 57600;                // 16
  float* part2  = ws + 57616;                // 32*16384 = 524288
  float* part2S = ws + 57616 + 524288;       // 4096
  float* partG  = ws + 57616 + 524288 + 4096;

  const size_t wsf = ws_size / 4;
  long avail = (long)wsf - (57616 + 524288 + 4096);
  int slots = (int)(avail / (16384 + 128));
  if (slots > 512) slots = 512;
  if (slots < 1) slots = 1;
  float* partS = partG + (size_t)slots * 16384;

  gram_k<<<slots, 512, 0, stream>>>(x, partG, partS, slots);
  reduce1_k<<<512, 256, 0, stream>>>(partG, partS, part2, part2S, slots);
  sigred_k<<<16, 256, 0, stream>>>(part2, part2S, Sigma, traceP, Sb);
  newton1_k<<<16, 256, 0, stream>>>(Sigma, traceP, Pb);         // -> P2
  newton_k<<<16, 256, 0, stream>>>(Pb, Sigma, traceP, Pa);      // -> P3
  newton_k<<<16, 256, 0, stream>>>(Pa, Sigma, traceP, Pb);      // -> P4
  newton_k<<<16, 256, 0, stream>>>(Pb, Sigma, traceP, Pa);      // -> P5
  rotmt_k<<<16, 256, 0, stream>>>(rot, Pa, Sb, traceP, Mbf, bias);
  apply_k<<<3136, 256, 0, stream>>>(x, Mbf, bias, out);
}